// Round 1
// baseline (153.279 us; speedup 1.0000x reference)
//
#include <hip/hip_runtime.h>
#include <cmath>

// SSIM fused kernel for B=16, C=3, H=W=512 fp32 images.
// Separable 11-tap Gaussian. R-next: TWO output columns per thread.
//  - Horizontal conv windows of cols 2t,2t+1 overlap in 10/11 taps: one
//    thread reads 12 taps (6x aligned ds_read_b128) instead of 2x11
//    ds_read_b64 -> -45% LDS bytes, -73% LDS instrs, and the per-tap
//    sq/pr (3 VALU) is shared across both columns (-20% horiz VALU).
//  - Block = 256 threads (4 waves); 768 blocks at ~3 blocks/CU -> ALL
//    blocks co-resident, cross-block overlap fills barrier bubbles.
//  - Vertical: per-thread register ring of FOUR quantities x 2 columns
//    (88 floats), static-indexed via the (j+1+k)%11 unroll trick.
// launch_bounds(256,3): VGPR cap ~170 so the 88-float ring stays in
// VGPRs (the (512,4) 64-VGPR cap previously forced AGPR churn).

#define IMG_H 512
#define IMG_W 512
#define STRIPE 32
#define NSTR (IMG_H / STRIPE)      // 16
#define NPLANES 48                 // 16*3
#define NBLOCKS (NPLANES * NSTR)   // 768
#define SSIM_C1 (0.01f * 0.01f)
#define SSIM_C2 (0.03f * 0.03f)

struct W11 { float w[11]; };

__launch_bounds__(256, 3)
__global__ void ssim_main(const float* __restrict__ img1,
                          const float* __restrict__ img2,
                          float* __restrict__ blockSums, W11 wv) {
    // interleaved (a,b) pairs; slots 0..521 used (5 halo each side), pad 528
    __shared__ __align__(16) float2 tb[2][528];
    __shared__ float red[4];

    const int t = threadIdx.x;            // 0..255, columns 2t and 2t+1
    const int bid = blockIdx.x;
    const int plane = bid >> 4;           // /NSTR
    const int stripe = bid & (NSTR - 1);
    const int y0 = stripe * STRIPE;
    const size_t base = (size_t)plane * (IMG_H * IMG_W);

    // zero halo pads (slots 0..4 and 517..521, both buffers)
    if (t < 10) {
        const int col = (t < 5) ? t : (t + 512);
        tb[0][col] = make_float2(0.f, 0.f);
        tb[1][col] = make_float2(0.f, 0.f);
    }

    // vertical ring buffers (2 columns x 4 quantities), static-indexed
    float rA0[11], rB0[11], rS0[11], rP0[11];
    float rA1[11], rB1[11], rS1[11], rP1[11];
    float acc = 0.f;

    // prefetch first row (r = y0-5): float2 = both columns of one image
    float2 pa = make_float2(0.f, 0.f), pb = make_float2(0.f, 0.f);
    {
        const int r0 = y0 - 5;
        if (r0 >= 0) {
            pa = *(const float2*)(img1 + base + (size_t)r0 * IMG_W + 2 * t);
            pb = *(const float2*)(img2 + base + (size_t)r0 * IMG_W + 2 * t);
        }
    }

    int buf = 0;
#pragma unroll 1
    for (int c = 0; c < 4; ++c) {
#pragma unroll
        for (int j = 0; j < 11; ++j) {
            const int i = c * 11 + j;      // 0..43; only 0..41 do work
            if (i < 42) {                  // block-uniform guard
                // stage current row: slot = col + 5 (interleaved a,b)
                tb[buf][2 * t + 5] = make_float2(pa.x, pb.x);
                tb[buf][2 * t + 6] = make_float2(pa.y, pb.y);
                // prefetch next row (hidden behind barrier + compute)
                pa = make_float2(0.f, 0.f); pb = make_float2(0.f, 0.f);
                const int rn = y0 - 4 + i;
                if (i + 1 < 42 && rn >= 0 && rn < IMG_H) {
                    pa = *(const float2*)(img1 + base + (size_t)rn * IMG_W + 2 * t);
                    pb = *(const float2*)(img2 + base + (size_t)rn * IMG_W + 2 * t);
                }
                __syncthreads();

                // 12 taps as 6 aligned ds_read_b128 (slots 2t+0 .. 2t+11)
                float ta[12], tbv[12];
#pragma unroll
                for (int k = 0; k < 6; ++k) {
                    const float4 q = *(const float4*)(&tb[buf][2 * t + 2 * k]);
                    ta[2 * k]     = q.x; tbv[2 * k]     = q.y;
                    ta[2 * k + 1] = q.z; tbv[2 * k + 1] = q.w;
                }
                // horizontal 11-tap conv for both columns; sq/pr shared
                float hA0 = 0.f, hB0 = 0.f, hS0 = 0.f, hP0 = 0.f;
                float hA1 = 0.f, hB1 = 0.f, hS1 = 0.f, hP1 = 0.f;
#pragma unroll
                for (int m = 0; m < 12; ++m) {
                    const float a = ta[m], b = tbv[m];
                    const float sq = fmaf(b, b, a * a);  // a^2+b^2
                    const float pr = a * b;              // a*b
                    if (m <= 10) {                       // col0 taps 0..10
                        const float w = wv.w[m];
                        hA0 = fmaf(w, a, hA0);
                        hB0 = fmaf(w, b, hB0);
                        hS0 = fmaf(w, sq, hS0);
                        hP0 = fmaf(w, pr, hP0);
                    }
                    if (m >= 1) {                        // col1 taps 1..11
                        const float w = wv.w[m - 1];
                        hA1 = fmaf(w, a, hA1);
                        hB1 = fmaf(w, b, hB1);
                        hS1 = fmaf(w, sq, hS1);
                        hP1 = fmaf(w, pr, hP1);
                    }
                }
                rA0[j] = hA0; rB0[j] = hB0; rS0[j] = hS0; rP0[j] = hP0;
                rA1[j] = hA1; rB1[j] = hB1; rS1[j] = hS1; rP1[j] = hP1;

                if (i >= 10) {  // uniform; output row y = y0 + i - 10
                    float vA0 = 0.f, vB0 = 0.f, vS0 = 0.f, vP0 = 0.f;
                    float vA1 = 0.f, vB1 = 0.f, vS1 = 0.f, vP1 = 0.f;
#pragma unroll
                    for (int k = 0; k < 11; ++k) {
                        const int s = (j + 1 + k) % 11;  // static per (j,k)
                        const float w = wv.w[k];
                        vA0 = fmaf(w, rA0[s], vA0);
                        vB0 = fmaf(w, rB0[s], vB0);
                        vS0 = fmaf(w, rS0[s], vS0);
                        vP0 = fmaf(w, rP0[s], vP0);
                        vA1 = fmaf(w, rA1[s], vA1);
                        vB1 = fmaf(w, rB1[s], vB1);
                        vS1 = fmaf(w, rS1[s], vS1);
                        vP1 = fmaf(w, rP1[s], vP1);
                    }
                    {
                        const float mu11 = vA0 * vA0;
                        const float mu22 = vB0 * vB0;
                        const float mu12 = vA0 * vB0;
                        const float num = fmaf(2.f, mu12, SSIM_C1) *
                                          fmaf(2.f, vP0 - mu12, SSIM_C2);
                        const float d1  = mu11 + mu22;
                        const float den = (d1 + SSIM_C1) * ((vS0 - d1) + SSIM_C2);
                        acc = fmaf(num, __builtin_amdgcn_rcpf(den), acc);
                    }
                    {
                        const float mu11 = vA1 * vA1;
                        const float mu22 = vB1 * vB1;
                        const float mu12 = vA1 * vB1;
                        const float num = fmaf(2.f, mu12, SSIM_C1) *
                                          fmaf(2.f, vP1 - mu12, SSIM_C2);
                        const float d1  = mu11 + mu22;
                        const float den = (d1 + SSIM_C1) * ((vS1 - d1) + SSIM_C2);
                        acc = fmaf(num, __builtin_amdgcn_rcpf(den), acc);
                    }
                }
                buf ^= 1;
            }
        }
    }

    // block reduction: wave shuffle, then 4 wave-sums via LDS
#pragma unroll
    for (int off = 32; off >= 1; off >>= 1)
        acc += __shfl_down(acc, off, 64);
    const int wave = t >> 6, lane = t & 63;
    if (lane == 0) red[wave] = acc;
    __syncthreads();
    if (t == 0) blockSums[bid] = red[0] + red[1] + red[2] + red[3];
}

__global__ void ssim_reduce(const float* __restrict__ bs,
                            float* __restrict__ out) {
    __shared__ double red[4];
    const int t = threadIdx.x;  // 256 threads
    double a = 0.0;
    for (int idx = t; idx < NBLOCKS; idx += 256) a += (double)bs[idx];
#pragma unroll
    for (int off = 32; off >= 1; off >>= 1)
        a += __shfl_down(a, off, 64);
    const int wave = t >> 6, lane = t & 63;
    if (lane == 0) red[wave] = a;
    __syncthreads();
    if (t == 0) {
        const double s = red[0] + red[1] + red[2] + red[3];
        out[0] = (float)(s / (double)((double)NPLANES * IMG_H * IMG_W));
    }
}

extern "C" void kernel_launch(void* const* d_in, const int* in_sizes, int n_in,
                              void* d_out, int out_size, void* d_ws, size_t ws_size,
                              hipStream_t stream) {
    const float* img1 = (const float*)d_in[0];
    const float* img2 = (const float*)d_in[1];
    float* out = (float*)d_out;
    float* bs = (float*)d_ws;   // 768 floats of scratch

    // Gaussian weights, faithful to reference: center 5.5, sigma 1.5
    W11 wv;
    double g[11], s = 0.0;
    for (int i = 0; i < 11; ++i) {
        const double d = (double)i - 5.5;
        g[i] = exp(-(d * d) / (2.0 * 1.5 * 1.5));
        s += g[i];
    }
    for (int i = 0; i < 11; ++i) wv.w[i] = (float)(g[i] / s);

    ssim_main<<<NBLOCKS, 256, 0, stream>>>(img1, img2, bs, wv);
    ssim_reduce<<<1, 256, 0, stream>>>(bs, out);
}

// Round 2
// 149.530 us; speedup vs baseline: 1.0251x; 1.0251x over previous
//
#include <hip/hip_runtime.h>
#include <cmath>

// SSIM fused kernel for B=16, C=3, H=W=512 fp32 images.
// R2: revert to the proven 512-thread / 1-col-per-thread structure (R1's
// 2-col attempt spilled its 88-float ring: VGPR=84 < ring size, WRITE_SIZE
// 24->1560 KB scratch traffic, occupancy 33->24%, net regression).
// New in R2: the four accumulator chains (A,B) / (S,P) are expressed as
// f32x2 packed chains -> v_pk_fma_f32 (VOP3P, gfx90a+). Horizontal conv
// 77->55 VALU/row, vertical 57->35 per output row. Ring stays 44 floats
// (22 f32x2), same pressure as the 52-VGPR R0 kernel.
// Weights passed pre-broadcast as float2{w,w} so packed sources are SGPR
// pairs.
//
// launch_bounds(512,2): 2 waves/EU -> 128 VGPR cap; at (512,4) the 64-VGPR
// cap forced the ring into AGPR churn (measured in an earlier session).

#define IMG_H 512
#define IMG_W 512
#define STRIPE 32
#define NSTR (IMG_H / STRIPE)      // 16
#define NPLANES 48                 // 16*3
#define NBLOCKS (NPLANES * NSTR)   // 768
#define SSIM_C1 (0.01f * 0.01f)
#define SSIM_C2 (0.03f * 0.03f)

typedef float f32x2 __attribute__((ext_vector_type(2)));

struct W2x11 { float2 w[11]; };   // pre-broadcast {w,w} pairs

__launch_bounds__(512, 2)
__global__ void ssim_main(const float* __restrict__ img1,
                          const float* __restrict__ img2,
                          float* __restrict__ blockSums, W2x11 wv) {
    // interleaved (a,b) pairs; cols 0..521 used (5 halo each side), pad 528
    __shared__ float2 tb[2][528];
    __shared__ float red[8];

    const int x = threadIdx.x;            // 0..511, one output column
    const int bid = blockIdx.x;
    const int plane = bid >> 4;           // /NSTR
    const int stripe = bid & (NSTR - 1);
    const int y0 = stripe * STRIPE;
    const size_t base = (size_t)plane * (IMG_H * IMG_W);

    // zero halo pads (cols 0..4 and 517..521, both buffers)
    if (x < 10) {
        const int col = (x < 5) ? x : (x + 512);
        tb[0][col] = make_float2(0.f, 0.f);
        tb[1][col] = make_float2(0.f, 0.f);
    }

    // vertical ring buffers as packed pairs, static-indexed via unroll
    f32x2 rAB[11], rSP[11];
    float acc = 0.f;

    // prefetch first row (r = y0-5)
    float pa = 0.f, pb = 0.f;
    {
        const int r0 = y0 - 5;
        if (r0 >= 0) {
            pa = img1[base + (size_t)r0 * IMG_W + x];
            pb = img2[base + (size_t)r0 * IMG_W + x];
        }
    }

    int buf = 0;
#pragma unroll 1
    for (int c = 0; c < 4; ++c) {
#pragma unroll
        for (int j = 0; j < 11; ++j) {
            const int i = c * 11 + j;      // 0..43; only 0..41 do work
            if (i < 42) {                  // block-uniform guard
                // stage current row into LDS as interleaved pair
                tb[buf][x + 5] = make_float2(pa, pb);
                // prefetch next row (hidden behind barrier + compute)
                pa = 0.f; pb = 0.f;
                const int rn = y0 - 4 + i;
                if (i + 1 < 42 && rn >= 0 && rn < IMG_H) {
                    pa = img1[base + (size_t)rn * IMG_W + x];
                    pb = img2[base + (size_t)rn * IMG_W + x];
                }
                __syncthreads();
                // horizontal 11-tap conv; (A,B) and (S,P) packed
                f32x2 hAB = {0.f, 0.f}, hSP = {0.f, 0.f};
#pragma unroll
                for (int k = 0; k < 11; ++k) {
                    const float2 t = tb[buf][x + k];   // ds_read_b64
                    f32x2 ab; ab.x = t.x; ab.y = t.y;
                    f32x2 sp;
                    sp.x = fmaf(t.y, t.y, t.x * t.x);  // a^2+b^2
                    sp.y = t.x * t.y;                  // a*b
                    f32x2 w2; w2.x = wv.w[k].x; w2.y = wv.w[k].y;
                    hAB = __builtin_elementwise_fma(w2, ab, hAB);
                    hSP = __builtin_elementwise_fma(w2, sp, hSP);
                }
                rAB[j] = hAB; rSP[j] = hSP;

                if (i >= 10) {  // uniform; output row y = y0 + i - 10
                    f32x2 vAB = {0.f, 0.f}, vSP = {0.f, 0.f};
#pragma unroll
                    for (int k = 0; k < 11; ++k) {
                        const int s = (j + 1 + k) % 11;  // static per (j,k)
                        f32x2 w2; w2.x = wv.w[k].x; w2.y = wv.w[k].y;
                        vAB = __builtin_elementwise_fma(w2, rAB[s], vAB);
                        vSP = __builtin_elementwise_fma(w2, rSP[s], vSP);
                    }
                    const float vA = vAB.x, vB = vAB.y;
                    const float vS = vSP.x, vP = vSP.y;
                    const float mu11 = vA * vA;
                    const float mu22 = vB * vB;
                    const float mu12 = vA * vB;
                    const float num = fmaf(2.f, mu12, SSIM_C1) *
                                      fmaf(2.f, vP - mu12, SSIM_C2);
                    const float d1  = mu11 + mu22;
                    const float den = (d1 + SSIM_C1) * ((vS - d1) + SSIM_C2);
                    acc = fmaf(num, __builtin_amdgcn_rcpf(den), acc);
                }
                buf ^= 1;
            }
        }
    }

    // block reduction: wave shuffle, then 8 wave-sums via LDS
#pragma unroll
    for (int off = 32; off >= 1; off >>= 1)
        acc += __shfl_down(acc, off, 64);
    const int wave = x >> 6, lane = x & 63;
    if (lane == 0) red[wave] = acc;
    __syncthreads();
    if (x == 0) {
        float s = 0.f;
#pragma unroll
        for (int k = 0; k < 8; ++k) s += red[k];
        blockSums[bid] = s;
    }
}

__global__ void ssim_reduce(const float* __restrict__ bs,
                            float* __restrict__ out) {
    __shared__ double red[4];
    const int t = threadIdx.x;  // 256 threads
    double a = 0.0;
    for (int idx = t; idx < NBLOCKS; idx += 256) a += (double)bs[idx];
#pragma unroll
    for (int off = 32; off >= 1; off >>= 1)
        a += __shfl_down(a, off, 64);
    const int wave = t >> 6, lane = t & 63;
    if (lane == 0) red[wave] = a;
    __syncthreads();
    if (t == 0) {
        const double s = red[0] + red[1] + red[2] + red[3];
        out[0] = (float)(s / (double)((double)NPLANES * IMG_H * IMG_W));
    }
}

extern "C" void kernel_launch(void* const* d_in, const int* in_sizes, int n_in,
                              void* d_out, int out_size, void* d_ws, size_t ws_size,
                              hipStream_t stream) {
    const float* img1 = (const float*)d_in[0];
    const float* img2 = (const float*)d_in[1];
    float* out = (float*)d_out;
    float* bs = (float*)d_ws;   // 768 floats of scratch

    // Gaussian weights, faithful to reference: center 5.5, sigma 1.5
    W2x11 wv;
    double g[11], s = 0.0;
    for (int i = 0; i < 11; ++i) {
        const double d = (double)i - 5.5;
        g[i] = exp(-(d * d) / (2.0 * 1.5 * 1.5));
        s += g[i];
    }
    for (int i = 0; i < 11; ++i) {
        const float w = (float)(g[i] / s);
        wv.w[i] = make_float2(w, w);
    }

    ssim_main<<<NBLOCKS, 512, 0, stream>>>(img1, img2, bs, wv);
    ssim_reduce<<<1, 256, 0, stream>>>(bs, out);
}